// Round 3
// 593.052 us; speedup vs baseline: 1.1640x; 1.1640x over previous
//
#include <hip/hip_runtime.h>
#include <cstddef>

// Problem constants (B, L, D, H, HD) = (2, 2048, 768, 12, 64)
#define Bc   2
#define Lc   2048
#define Dc   768
#define Hc   12
#define HDc  64
#define Mrows (Bc * Lc)
#define PAD  72   // ushorts; 144 B row stride keeps b128 reads bank-balanced & 16B-aligned

typedef _Float16 half8 __attribute__((ext_vector_type(8)));
typedef unsigned short ushort8 __attribute__((ext_vector_type(8)));
typedef __attribute__((ext_vector_type(4))) float floatx4;

__device__ __forceinline__ float silu_f(float x) {
    return x / (1.0f + __expf(-x));
}
__device__ __forceinline__ unsigned short f2h(float x) {
    _Float16 h = (_Float16)x;                       // v_cvt_f16_f32, RNE
    return __builtin_bit_cast(unsigned short, h);
}

// ---------------------------------------------------------------------------
// Fused QKV projection: y = silu(hs @ W^T), RoPE fused for Q/K, V stored ^T.
// grid (36, 64): x = which*12 + n-block (which: 0=Q 1=K 2=V), y = m-block.
// 64x64 tile, 4 waves, K = 768 in 12 chunks of 64.
// The 64 output columns of a block are exactly one head (HD=64), and the RoPE
// pair (hd, hd+32) is exactly (acc[nn], acc[nn+2]) -> rope is free in epilogue.
// ---------------------------------------------------------------------------
__global__ __launch_bounds__(256)
void gemm_qkv(const float* __restrict__ hs,
              const float* __restrict__ Wq, const float* __restrict__ Wk,
              const float* __restrict__ Wv,
              const float* __restrict__ cosb, const float* __restrict__ sinb,
              unsigned short* __restrict__ q16, unsigned short* __restrict__ k16,
              unsigned short* __restrict__ vT16) {
    __shared__ unsigned short Af[64][PAD];
    __shared__ unsigned short Wf[64][PAD];
    const int tid  = threadIdx.x;
    const int lane = tid & 63, w = tid >> 6;
    const int m = lane & 15, quad = lane >> 4;
    const int m0 = blockIdx.y * 64;
    const int nblk = blockIdx.x;
    const int which = nblk / 12;                    // 0=Q 1=K 2=V (block-uniform)
    const int n0 = (nblk - which * 12) * 64;        // column offset within its matrix
    const float* __restrict__ W = (which == 0) ? Wq : (which == 1) ? Wk : Wv;

    floatx4 acc[4] = {{0.f,0.f,0.f,0.f},{0.f,0.f,0.f,0.f},
                      {0.f,0.f,0.f,0.f},{0.f,0.f,0.f,0.f}};

    for (int kc = 0; kc < Dc; kc += 64) {
        __syncthreads();
#pragma unroll
        for (int p = 0; p < 4; ++p) {
            const int f = tid + p * 256;
            const int row = f >> 4, c4 = (f & 15) << 2;
            const float4 ta = *(const float4*)(hs + (size_t)(m0 + row) * Dc + kc + c4);
            *(ushort4*)&Af[row][c4] = make_ushort4(f2h(ta.x), f2h(ta.y), f2h(ta.z), f2h(ta.w));
            const float4 tw = *(const float4*)(W + (size_t)(n0 + row) * Dc + kc + c4);
            *(ushort4*)&Wf[row][c4] = make_ushort4(f2h(tw.x), f2h(tw.y), f2h(tw.z), f2h(tw.w));
        }
        __syncthreads();

        const half8 a0 = *(const half8*)&Af[w * 16 + m][quad * 8];
        const half8 a1 = *(const half8*)&Af[w * 16 + m][32 + quad * 8];
#pragma unroll
        for (int nn = 0; nn < 4; ++nn) {
            const half8 b0 = *(const half8*)&Wf[nn * 16 + m][quad * 8];
            const half8 b1 = *(const half8*)&Wf[nn * 16 + m][32 + quad * 8];
            acc[nn] = __builtin_amdgcn_mfma_f32_16x16x32_f16(a0, b0, acc[nn], 0, 0, 0);
            acc[nn] = __builtin_amdgcn_mfma_f32_16x16x32_f16(a1, b1, acc[nn], 0, 0, 0);
        }
    }

    // D frag: col = n0 + nn*16 + m, row = m0 + w*16 + quad*4 + r.
    if (which < 2) {
        // Q or K: silu (fp32) -> RoPE (fp32) -> fp16 store to (b,h,l,hd)
        unsigned short* __restrict__ dst = which ? k16 : q16;
        const int h = n0 >> 6;                      // whole tile is one head
#pragma unroll
        for (int r = 0; r < 4; ++r) {
            const int row = m0 + w * 16 + quad * 4 + r;
            const int b = row >> 11, l = row & (Lc - 1);
            const size_t cb   = ((size_t)b * Lc + l) * HDc;
            const size_t base = ((size_t)(b * Hc + h) * Lc + l) * HDc;
            const float ya = silu_f(acc[0][r]);     // hd = m       (x1)
            const float yb = silu_f(acc[1][r]);     // hd = m+16    (x1)
            const float yc = silu_f(acc[2][r]);     // hd = m+32    (x2)
            const float yd = silu_f(acc[3][r]);     // hd = m+48    (x2)
            dst[base + m]      = f2h(ya * cosb[cb + m]      - yc * sinb[cb + m]);
            dst[base + m + 16] = f2h(yb * cosb[cb + m + 16] - yd * sinb[cb + m + 16]);
            dst[base + m + 32] = f2h(yc * cosb[cb + m + 32] + ya * sinb[cb + m + 32]);
            dst[base + m + 48] = f2h(yd * cosb[cb + m + 48] + yb * sinb[cb + m + 48]);
        }
    } else {
        // V: silu, fp16 store TRANSPOSED to (b,h,hd,l)
#pragma unroll
        for (int nn = 0; nn < 4; ++nn) {
            const int col = n0 + nn * 16 + m;
            const int h = col >> 6, hd = col & 63;
            const int row0 = m0 + w * 16 + quad * 4;
            const int b = row0 >> 11, l0 = row0 & (Lc - 1);
            const ushort4 hh = make_ushort4(f2h(silu_f(acc[nn][0])), f2h(silu_f(acc[nn][1])),
                                            f2h(silu_f(acc[nn][2])), f2h(silu_f(acc[nn][3])));
            *(ushort4*)(vT16 + ((size_t)(b * Hc + h) * HDc + hd) * Lc + l0) = hh;
        }
    }
}

// ---------------------------------------------------------------------------
// Fused attention, fp16 MFMA, register-staged double buffering (T14):
// issue kt+1's K/V global loads BEFORE compute, write them to LDS AFTER the
// read-complete barrier. Ps is wave-private (rows [16w,16w+16)) -> no barrier
// between phase 1 and phase 2. attn stores are nontemporal (don't evict K/V).
// ---------------------------------------------------------------------------
__global__ __launch_bounds__(256)
void attn_kernel(const unsigned short* __restrict__ q16,
                 const unsigned short* __restrict__ k16,
                 const unsigned short* __restrict__ vT16,
                 float* __restrict__ attn_out,
                 unsigned short* __restrict__ o16) {
    __shared__ unsigned short Qf[64][PAD];   // [q][hd]
    __shared__ unsigned short Kf[64][PAD];   // [kj][hd]
    __shared__ unsigned short Vt[64][PAD];   // [hd][kj]
    __shared__ unsigned short Ps[64][PAD];   // [q][kj]  (wave-private rows)

    const int tid  = threadIdx.x;
    const int lane = tid & 63, w = tid >> 6;
    const int m = lane & 15, quad = lane >> 4;
    const int qt = gridDim.x - 1 - blockIdx.x;      // big causal rows first
    const int bh = blockIdx.y;
    const int b = bh / Hc, h = bh - b * Hc;
    const size_t qkv = (size_t)bh * Lc * HDc;
    const float invL = 1.0f / (float)Lc;

    // staging geometry: 8 threads per row, 16B each -> 1 KB contiguous per wave
    const int srow = tid >> 3, sc8 = (tid & 7) << 3;
    const unsigned short* kbase = k16 + qkv;
    const unsigned short* vbase = vT16 + (size_t)bh * HDc * Lc;

    // Stage Q tile (fp16, 8 KB)
    {
        const unsigned short* qp = q16 + qkv + (size_t)(qt * 64) * HDc;
        *(ushort8*)&Qf[srow][sc8]      = *(const ushort8*)(qp + srow * HDc + sc8);
        *(ushort8*)&Qf[srow + 32][sc8] = *(const ushort8*)(qp + (srow + 32) * HDc + sc8);
    }

    // Prologue: load + LDS-write tile kt=0
    ushort8 kreg0, kreg1, vreg0, vreg1;
    kreg0 = *(const ushort8*)(kbase + srow * HDc + sc8);
    kreg1 = *(const ushort8*)(kbase + (srow + 32) * HDc + sc8);
    vreg0 = *(const ushort8*)(vbase + (size_t)srow * Lc + sc8);
    vreg1 = *(const ushort8*)(vbase + (size_t)(srow + 32) * Lc + sc8);
    *(ushort8*)&Kf[srow][sc8]      = kreg0;
    *(ushort8*)&Kf[srow + 32][sc8] = kreg1;
    *(ushort8*)&Vt[srow][sc8]      = vreg0;
    *(ushort8*)&Vt[srow + 32][sc8] = vreg1;
    __syncthreads();                                // Qf + tile 0 visible

    // Q as B-operand (fixed per wave): n = q = w*16 + m, k = hd
    const half8 bq0 = *(const half8*)&Qf[w * 16 + m][quad * 8];
    const half8 bq1 = *(const half8*)&Qf[w * 16 + m][32 + quad * 8];

    floatx4 oacc[4] = {{0.f,0.f,0.f,0.f},{0.f,0.f,0.f,0.f},
                       {0.f,0.f,0.f,0.f},{0.f,0.f,0.f,0.f}};
    float* attn_base = attn_out + (size_t)bh * Lc * Lc;
    const int gi = qt * 64 + w * 16 + m;            // this lane's q row

    for (int kt = 0; kt <= qt; ++kt) {
        // ---- async-stage: issue kt+1 loads now; latency hides under MFMA ----
        if (kt < qt) {
            const unsigned short* kp = kbase + (size_t)((kt + 1) * 64) * HDc;
            const unsigned short* vp = vbase + (kt + 1) * 64;
            kreg0 = *(const ushort8*)(kp + srow * HDc + sc8);
            kreg1 = *(const ushort8*)(kp + (srow + 32) * HDc + sc8);
            vreg0 = *(const ushort8*)(vp + (size_t)srow * Lc + sc8);
            vreg1 = *(const ushort8*)(vp + (size_t)(srow + 32) * Lc + sc8);
        }

        // ---- Phase 1: S^T[kj][q] = sum_hd K[kj][hd] * Q[q][hd] ----
        const bool diag = (kt == qt);
#pragma unroll
        for (int mm = 0; mm < 4; ++mm) {
            const half8 ak0 = *(const half8*)&Kf[mm * 16 + m][quad * 8];
            const half8 ak1 = *(const half8*)&Kf[mm * 16 + m][32 + quad * 8];
            floatx4 s = {0.f, 0.f, 0.f, 0.f};
            s = __builtin_amdgcn_mfma_f32_16x16x32_f16(ak0, bq0, s, 0, 0, 0);
            s = __builtin_amdgcn_mfma_f32_16x16x32_f16(ak1, bq1, s, 0, 0, 0);
            // D: col = q = w*16+m (fixed), row = kj = mm*16 + quad*4 + r
            const int kj0 = mm * 16 + quad * 4;
            const int gj0 = kt * 64 + kj0;
            float v[4];
#pragma unroll
            for (int r = 0; r < 4; ++r) {
                float val = s[r];
                v[r] = (diag && (gj0 + r) > gi) ? 0.0f : silu_f(val) * invL;
            }
            const floatx4 vv = {v[0], v[1], v[2], v[3]};
            __builtin_nontemporal_store(vv, (floatx4*)(attn_base + (size_t)gi * Lc + gj0));
            *(ushort4*)&Ps[w * 16 + m][kj0] = make_ushort4(f2h(v[0]), f2h(v[1]), f2h(v[2]), f2h(v[3]));
        }

        // ---- Phase 2 (no barrier: Ps rows are wave-private, DS is in-order) ----
        const half8 ap0 = *(const half8*)&Ps[w * 16 + m][quad * 8];
        const half8 ap1 = *(const half8*)&Ps[w * 16 + m][32 + quad * 8];
#pragma unroll
        for (int nn = 0; nn < 4; ++nn) {
            const half8 bv0 = *(const half8*)&Vt[nn * 16 + m][quad * 8];
            const half8 bv1 = *(const half8*)&Vt[nn * 16 + m][32 + quad * 8];
            oacc[nn] = __builtin_amdgcn_mfma_f32_16x16x32_f16(ap0, bv0, oacc[nn], 0, 0, 0);
            oacc[nn] = __builtin_amdgcn_mfma_f32_16x16x32_f16(ap1, bv1, oacc[nn], 0, 0, 0);
        }

        __syncthreads();                            // all waves done reading Kf/Vt(kt)
        if (kt < qt) {
            *(ushort8*)&Kf[srow][sc8]      = kreg0; // compiler waits only on the 4 loads
            *(ushort8*)&Kf[srow + 32][sc8] = kreg1;
            *(ushort8*)&Vt[srow][sc8]      = vreg0;
            *(ushort8*)&Vt[srow + 32][sc8] = vreg1;
            __syncthreads();                        // tile kt+1 visible
        }
    }

    // Zero-fill strictly-upper tiles (silu(-1e9)/L == -0.0)
    {
        const int tx = tid & 15, ty = tid >> 4;
        const floatx4 z = {0.f, 0.f, 0.f, 0.f};
#pragma unroll 1
        for (int kt2 = qt + 1; kt2 < Lc / 64; ++kt2) {
#pragma unroll
            for (int i = 0; i < 4; ++i) {
                const int gi2 = qt * 64 + (ty << 2) + i;
                __builtin_nontemporal_store(z,
                    (floatx4*)(attn_base + (size_t)gi2 * Lc + kt2 * 64 + (tx << 2)));
            }
        }
    }

    // out store: D col = hd = nn*16+m, row = q = w*16 + quad*4 + r
#pragma unroll
    for (int nn = 0; nn < 4; ++nn)
#pragma unroll
        for (int r = 0; r < 4; ++r) {
            const int gi2 = qt * 64 + w * 16 + quad * 4 + r;
            o16[((size_t)b * Lc + gi2) * Dc + h * HDc + nn * 16 + m] = f2h(oacc[nn][r]);
        }
}

// ---------------------------------------------------------------------------
// Output projection: attn_output[m][n] = sum_k o16[m][k] * Wo[n][k], fp32 out.
// ---------------------------------------------------------------------------
__global__ __launch_bounds__(256)
void gemm_out(const unsigned short* __restrict__ A16, const float* __restrict__ W,
              float* __restrict__ C) {
    __shared__ unsigned short Af[64][PAD];
    __shared__ unsigned short Wf[64][PAD];
    const int tid  = threadIdx.x;
    const int lane = tid & 63, w = tid >> 6;
    const int m = lane & 15, quad = lane >> 4;
    const int m0 = blockIdx.y * 64, n0 = blockIdx.x * 64;

    floatx4 acc[4] = {{0.f,0.f,0.f,0.f},{0.f,0.f,0.f,0.f},
                      {0.f,0.f,0.f,0.f},{0.f,0.f,0.f,0.f}};

    for (int kc = 0; kc < Dc; kc += 64) {
        __syncthreads();
#pragma unroll
        for (int p = 0; p < 2; ++p) {
            const int f = tid + p * 256;
            const int row = f >> 3, c8 = (f & 7) << 3;
            *(ushort8*)&Af[row][c8] = *(const ushort8*)(A16 + (size_t)(m0 + row) * Dc + kc + c8);
        }
#pragma unroll
        for (int p = 0; p < 4; ++p) {
            const int f = tid + p * 256;
            const int row = f >> 4, c4 = (f & 15) << 2;
            const float4 t = *(const float4*)(W + (size_t)(n0 + row) * Dc + kc + c4);
            *(ushort4*)&Wf[row][c4] = make_ushort4(f2h(t.x), f2h(t.y), f2h(t.z), f2h(t.w));
        }
        __syncthreads();

        const half8 a0 = *(const half8*)&Af[w * 16 + m][quad * 8];
        const half8 a1 = *(const half8*)&Af[w * 16 + m][32 + quad * 8];
#pragma unroll
        for (int nn = 0; nn < 4; ++nn) {
            const half8 b0 = *(const half8*)&Wf[nn * 16 + m][quad * 8];
            const half8 b1 = *(const half8*)&Wf[nn * 16 + m][32 + quad * 8];
            acc[nn] = __builtin_amdgcn_mfma_f32_16x16x32_f16(a0, b0, acc[nn], 0, 0, 0);
            acc[nn] = __builtin_amdgcn_mfma_f32_16x16x32_f16(a1, b1, acc[nn], 0, 0, 0);
        }
    }

#pragma unroll
    for (int nn = 0; nn < 4; ++nn) {
        const int col = n0 + nn * 16 + m;
#pragma unroll
        for (int r = 0; r < 4; ++r) {
            const int row = m0 + w * 16 + quad * 4 + r;
            __builtin_nontemporal_store(acc[nn][r], C + (size_t)row * Dc + col);
        }
    }
}

extern "C" void kernel_launch(void* const* d_in, const int* in_sizes, int n_in,
                              void* d_out, int out_size, void* d_ws, size_t ws_size,
                              hipStream_t stream) {
    const float* hs   = (const float*)d_in[0];
    const float* cosb = (const float*)d_in[2];
    const float* sinb = (const float*)d_in[3];
    const float* Wq   = (const float*)d_in[4];
    const float* Wk   = (const float*)d_in[5];
    const float* Wv   = (const float*)d_in[6];
    const float* Wo   = (const float*)d_in[7];

    float* attn_output = (float*)d_out;                         // (B,L,D)
    float* attn        = attn_output + (size_t)Mrows * Dc;      // (B,H,L,L)

    const size_t seg = (size_t)Bc * Hc * Lc * HDc;              // 3,145,728 elems
    unsigned short* q16  = (unsigned short*)d_ws;
    unsigned short* k16  = q16 + seg;
    unsigned short* vT16 = k16 + seg;                           // (b,h,hd,l)
    unsigned short* o16  = vT16 + seg;                          // (b,l,Dc)

    const dim3 blk(256);

    // 3 launches (was 6): fused QKV+RoPE+V^T, attention, output projection
    gemm_qkv<<<dim3(36, Mrows / 64), blk, 0, stream>>>(hs, Wq, Wk, Wv, cosb, sinb,
                                                       q16, k16, vT16);
    attn_kernel<<<dim3(Lc / 64, Bc * Hc), blk, 0, stream>>>(q16, k16, vT16, attn, o16);
    gemm_out<<<dim3(Dc / 64, Mrows / 64), blk, 0, stream>>>(o16, Wo, attn_output);
}

// Round 4
// 586.468 us; speedup vs baseline: 1.1771x; 1.0112x over previous
//
#include <hip/hip_runtime.h>
#include <cstddef>

// Problem constants (B, L, D, H, HD) = (2, 2048, 768, 12, 64)
#define Bc   2
#define Lc   2048
#define Dc   768
#define Hc   12
#define HDc  64
#define Mrows (Bc * Lc)
#define PAD  72   // ushorts; 144 B row stride keeps b128 reads bank-balanced & 16B-aligned

typedef _Float16 half8 __attribute__((ext_vector_type(8)));
typedef unsigned short ushort8 __attribute__((ext_vector_type(8)));
typedef __attribute__((ext_vector_type(4))) float floatx4;

__device__ __forceinline__ float silu_f(float x) {
    return x / (1.0f + __expf(-x));
}
__device__ __forceinline__ unsigned short f2h(float x) {
    _Float16 h = (_Float16)x;                       // v_cvt_f16_f32, RNE
    return __builtin_bit_cast(unsigned short, h);
}

// ---------------------------------------------------------------------------
// Fused QKV projection: y = silu(hs @ W^T), RoPE fused for Q/K, V stored ^T.
// grid (36, 64): x = which*12 + n-block (which: 0=Q 1=K 2=V), y = m-block.
// 64x64 tile, 4 waves, K = 768 in 12 chunks of 64.
// The 64 output columns of a block are exactly one head (HD=64), and the RoPE
// pair (hd, hd+32) is exactly (acc[nn], acc[nn+2]) -> rope is free in epilogue.
// ---------------------------------------------------------------------------
__global__ __launch_bounds__(256)
void gemm_qkv(const float* __restrict__ hs,
              const float* __restrict__ Wq, const float* __restrict__ Wk,
              const float* __restrict__ Wv,
              const float* __restrict__ cosb, const float* __restrict__ sinb,
              unsigned short* __restrict__ q16, unsigned short* __restrict__ k16,
              unsigned short* __restrict__ vT16) {
    __shared__ unsigned short Af[64][PAD];
    __shared__ unsigned short Wf[64][PAD];
    const int tid  = threadIdx.x;
    const int lane = tid & 63, w = tid >> 6;
    const int m = lane & 15, quad = lane >> 4;
    const int m0 = blockIdx.y * 64;
    const int nblk = blockIdx.x;
    const int which = nblk / 12;                    // 0=Q 1=K 2=V (block-uniform)
    const int n0 = (nblk - which * 12) * 64;        // column offset within its matrix
    const float* __restrict__ W = (which == 0) ? Wq : (which == 1) ? Wk : Wv;

    floatx4 acc[4] = {{0.f,0.f,0.f,0.f},{0.f,0.f,0.f,0.f},
                      {0.f,0.f,0.f,0.f},{0.f,0.f,0.f,0.f}};

    for (int kc = 0; kc < Dc; kc += 64) {
        __syncthreads();
#pragma unroll
        for (int p = 0; p < 4; ++p) {
            const int f = tid + p * 256;
            const int row = f >> 4, c4 = (f & 15) << 2;
            const float4 ta = *(const float4*)(hs + (size_t)(m0 + row) * Dc + kc + c4);
            *(ushort4*)&Af[row][c4] = make_ushort4(f2h(ta.x), f2h(ta.y), f2h(ta.z), f2h(ta.w));
            const float4 tw = *(const float4*)(W + (size_t)(n0 + row) * Dc + kc + c4);
            *(ushort4*)&Wf[row][c4] = make_ushort4(f2h(tw.x), f2h(tw.y), f2h(tw.z), f2h(tw.w));
        }
        __syncthreads();

        const half8 a0 = *(const half8*)&Af[w * 16 + m][quad * 8];
        const half8 a1 = *(const half8*)&Af[w * 16 + m][32 + quad * 8];
#pragma unroll
        for (int nn = 0; nn < 4; ++nn) {
            const half8 b0 = *(const half8*)&Wf[nn * 16 + m][quad * 8];
            const half8 b1 = *(const half8*)&Wf[nn * 16 + m][32 + quad * 8];
            acc[nn] = __builtin_amdgcn_mfma_f32_16x16x32_f16(a0, b0, acc[nn], 0, 0, 0);
            acc[nn] = __builtin_amdgcn_mfma_f32_16x16x32_f16(a1, b1, acc[nn], 0, 0, 0);
        }
    }

    // D frag: col = n0 + nn*16 + m, row = m0 + w*16 + quad*4 + r.
    if (which < 2) {
        // Q or K: silu (fp32) -> RoPE (fp32) -> fp16 store to (b,h,l,hd)
        unsigned short* __restrict__ dst = which ? k16 : q16;
        const int h = n0 >> 6;                      // whole tile is one head
#pragma unroll
        for (int r = 0; r < 4; ++r) {
            const int row = m0 + w * 16 + quad * 4 + r;
            const int b = row >> 11, l = row & (Lc - 1);
            const size_t cb   = ((size_t)b * Lc + l) * HDc;
            const size_t base = ((size_t)(b * Hc + h) * Lc + l) * HDc;
            const float ya = silu_f(acc[0][r]);     // hd = m       (x1)
            const float yb = silu_f(acc[1][r]);     // hd = m+16    (x1)
            const float yc = silu_f(acc[2][r]);     // hd = m+32    (x2)
            const float yd = silu_f(acc[3][r]);     // hd = m+48    (x2)
            dst[base + m]      = f2h(ya * cosb[cb + m]      - yc * sinb[cb + m]);
            dst[base + m + 16] = f2h(yb * cosb[cb + m + 16] - yd * sinb[cb + m + 16]);
            dst[base + m + 32] = f2h(yc * cosb[cb + m + 32] + ya * sinb[cb + m + 32]);
            dst[base + m + 48] = f2h(yd * cosb[cb + m + 48] + yb * sinb[cb + m + 48]);
        }
    } else {
        // V: silu, fp16 store TRANSPOSED to (b,h,hd,l)
#pragma unroll
        for (int nn = 0; nn < 4; ++nn) {
            const int col = n0 + nn * 16 + m;
            const int h = col >> 6, hd = col & 63;
            const int row0 = m0 + w * 16 + quad * 4;
            const int b = row0 >> 11, l0 = row0 & (Lc - 1);
            const ushort4 hh = make_ushort4(f2h(silu_f(acc[nn][0])), f2h(silu_f(acc[nn][1])),
                                            f2h(silu_f(acc[nn][2])), f2h(silu_f(acc[nn][3])));
            *(ushort4*)(vT16 + ((size_t)(b * Hc + h) * HDc + hd) * Lc + l0) = hh;
        }
    }
}

// ---------------------------------------------------------------------------
// Fused attention, fp16 MFMA, register-staged double buffering (T14).
// qt-BAND SWIZZLE: with grid (32, 24) = 768 blocks = 3/CU and round-robin
// dispatch, CU c hosts blocks {n, n+256, n+512} -> same blockIdx.x. The old
// qt = 31-x mapping gave one CU three qt=31 tiles (96 iter-units vs mean
// 49.5). Three band permutations A(x)=x, B(x)=(x+16)&31, C(x)=x<16?30-2x:
// 63-2x satisfy A+B+C in {46,47} for every x -> per-CU work 49/50 units
// (ideal 49.5), and zero-fill work (prop. 31-qt) is simultaneously constant.
// ---------------------------------------------------------------------------
__global__ __launch_bounds__(256)
void attn_kernel(const unsigned short* __restrict__ q16,
                 const unsigned short* __restrict__ k16,
                 const unsigned short* __restrict__ vT16,
                 float* __restrict__ attn_out,
                 unsigned short* __restrict__ o16) {
    __shared__ unsigned short Qf[64][PAD];   // [q][hd]
    __shared__ unsigned short Kf[64][PAD];   // [kj][hd]
    __shared__ unsigned short Vt[64][PAD];   // [hd][kj]
    __shared__ unsigned short Ps[64][PAD];   // [q][kj]  (wave-private rows)

    const int tid  = threadIdx.x;
    const int lane = tid & 63, w = tid >> 6;
    const int m = lane & 15, quad = lane >> 4;

    // balanced qt bands (see header comment)
    const int x = blockIdx.x;
    const int bh = blockIdx.y;
    const int band = bh >> 3;
    int qt;
    if (band == 0)      qt = x;
    else if (band == 1) qt = (x + 16) & 31;
    else                qt = (x < 16) ? (30 - 2 * x) : (63 - 2 * x);

    const int b = bh / Hc, h = bh - b * Hc;
    const size_t qkv = (size_t)bh * Lc * HDc;
    const float invL = 1.0f / (float)Lc;

    // staging geometry: 8 threads per row, 16B each -> 1 KB contiguous per wave
    const int srow = tid >> 3, sc8 = (tid & 7) << 3;
    const unsigned short* kbase = k16 + qkv;
    const unsigned short* vbase = vT16 + (size_t)bh * HDc * Lc;

    // Stage Q tile (fp16, 8 KB)
    {
        const unsigned short* qp = q16 + qkv + (size_t)(qt * 64) * HDc;
        *(ushort8*)&Qf[srow][sc8]      = *(const ushort8*)(qp + srow * HDc + sc8);
        *(ushort8*)&Qf[srow + 32][sc8] = *(const ushort8*)(qp + (srow + 32) * HDc + sc8);
    }

    // Prologue: load + LDS-write tile kt=0
    ushort8 kreg0, kreg1, vreg0, vreg1;
    kreg0 = *(const ushort8*)(kbase + srow * HDc + sc8);
    kreg1 = *(const ushort8*)(kbase + (srow + 32) * HDc + sc8);
    vreg0 = *(const ushort8*)(vbase + (size_t)srow * Lc + sc8);
    vreg1 = *(const ushort8*)(vbase + (size_t)(srow + 32) * Lc + sc8);
    *(ushort8*)&Kf[srow][sc8]      = kreg0;
    *(ushort8*)&Kf[srow + 32][sc8] = kreg1;
    *(ushort8*)&Vt[srow][sc8]      = vreg0;
    *(ushort8*)&Vt[srow + 32][sc8] = vreg1;
    __syncthreads();                                // Qf + tile 0 visible

    // Q as B-operand (fixed per wave): n = q = w*16 + m, k = hd
    const half8 bq0 = *(const half8*)&Qf[w * 16 + m][quad * 8];
    const half8 bq1 = *(const half8*)&Qf[w * 16 + m][32 + quad * 8];

    floatx4 oacc[4] = {{0.f,0.f,0.f,0.f},{0.f,0.f,0.f,0.f},
                       {0.f,0.f,0.f,0.f},{0.f,0.f,0.f,0.f}};
    float* attn_base = attn_out + (size_t)bh * Lc * Lc;
    const int gi = qt * 64 + w * 16 + m;            // this lane's q row

    for (int kt = 0; kt <= qt; ++kt) {
        // ---- async-stage: issue kt+1 loads now; latency hides under MFMA ----
        if (kt < qt) {
            const unsigned short* kp = kbase + (size_t)((kt + 1) * 64) * HDc;
            const unsigned short* vp = vbase + (kt + 1) * 64;
            kreg0 = *(const ushort8*)(kp + srow * HDc + sc8);
            kreg1 = *(const ushort8*)(kp + (srow + 32) * HDc + sc8);
            vreg0 = *(const ushort8*)(vp + (size_t)srow * Lc + sc8);
            vreg1 = *(const ushort8*)(vp + (size_t)(srow + 32) * Lc + sc8);
        }

        // ---- Phase 1: S^T[kj][q] = sum_hd K[kj][hd] * Q[q][hd] ----
        const bool diag = (kt == qt);
#pragma unroll
        for (int mm = 0; mm < 4; ++mm) {
            const half8 ak0 = *(const half8*)&Kf[mm * 16 + m][quad * 8];
            const half8 ak1 = *(const half8*)&Kf[mm * 16 + m][32 + quad * 8];
            floatx4 s = {0.f, 0.f, 0.f, 0.f};
            s = __builtin_amdgcn_mfma_f32_16x16x32_f16(ak0, bq0, s, 0, 0, 0);
            s = __builtin_amdgcn_mfma_f32_16x16x32_f16(ak1, bq1, s, 0, 0, 0);
            // D: col = q = w*16+m (fixed), row = kj = mm*16 + quad*4 + r
            const int kj0 = mm * 16 + quad * 4;
            const int gj0 = kt * 64 + kj0;
            float v[4];
#pragma unroll
            for (int r = 0; r < 4; ++r) {
                float val = s[r];
                v[r] = (diag && (gj0 + r) > gi) ? 0.0f : silu_f(val) * invL;
            }
            const floatx4 vv = {v[0], v[1], v[2], v[3]};
            __builtin_nontemporal_store(vv, (floatx4*)(attn_base + (size_t)gi * Lc + gj0));
            *(ushort4*)&Ps[w * 16 + m][kj0] = make_ushort4(f2h(v[0]), f2h(v[1]), f2h(v[2]), f2h(v[3]));
        }

        // ---- Phase 2 (no barrier: Ps rows are wave-private, DS is in-order) ----
        const half8 ap0 = *(const half8*)&Ps[w * 16 + m][quad * 8];
        const half8 ap1 = *(const half8*)&Ps[w * 16 + m][32 + quad * 8];
#pragma unroll
        for (int nn = 0; nn < 4; ++nn) {
            const half8 bv0 = *(const half8*)&Vt[nn * 16 + m][quad * 8];
            const half8 bv1 = *(const half8*)&Vt[nn * 16 + m][32 + quad * 8];
            oacc[nn] = __builtin_amdgcn_mfma_f32_16x16x32_f16(ap0, bv0, oacc[nn], 0, 0, 0);
            oacc[nn] = __builtin_amdgcn_mfma_f32_16x16x32_f16(ap1, bv1, oacc[nn], 0, 0, 0);
        }

        __syncthreads();                            // all waves done reading Kf/Vt(kt)
        if (kt < qt) {
            *(ushort8*)&Kf[srow][sc8]      = kreg0; // compiler waits only on the 4 loads
            *(ushort8*)&Kf[srow + 32][sc8] = kreg1;
            *(ushort8*)&Vt[srow][sc8]      = vreg0;
            *(ushort8*)&Vt[srow + 32][sc8] = vreg1;
            __syncthreads();                        // tile kt+1 visible
        }
    }

    // Zero-fill strictly-upper tiles (silu(-1e9)/L == -0.0)
    {
        const int tx = tid & 15, ty = tid >> 4;
        const floatx4 z = {0.f, 0.f, 0.f, 0.f};
#pragma unroll 1
        for (int kt2 = qt + 1; kt2 < Lc / 64; ++kt2) {
#pragma unroll
            for (int i = 0; i < 4; ++i) {
                const int gi2 = qt * 64 + (ty << 2) + i;
                __builtin_nontemporal_store(z,
                    (floatx4*)(attn_base + (size_t)gi2 * Lc + kt2 * 64 + (tx << 2)));
            }
        }
    }

    // out store: D col = hd = nn*16+m, row = q = w*16 + quad*4 + r
#pragma unroll
    for (int nn = 0; nn < 4; ++nn)
#pragma unroll
        for (int r = 0; r < 4; ++r) {
            const int gi2 = qt * 64 + w * 16 + quad * 4 + r;
            o16[((size_t)b * Lc + gi2) * Dc + h * HDc + nn * 16 + m] = f2h(oacc[nn][r]);
        }
}

// ---------------------------------------------------------------------------
// Output projection: attn_output[m][n] = sum_k o16[m][k] * Wo[n][k], fp32 out.
// ---------------------------------------------------------------------------
__global__ __launch_bounds__(256)
void gemm_out(const unsigned short* __restrict__ A16, const float* __restrict__ W,
              float* __restrict__ C) {
    __shared__ unsigned short Af[64][PAD];
    __shared__ unsigned short Wf[64][PAD];
    const int tid  = threadIdx.x;
    const int lane = tid & 63, w = tid >> 6;
    const int m = lane & 15, quad = lane >> 4;
    const int m0 = blockIdx.y * 64, n0 = blockIdx.x * 64;

    floatx4 acc[4] = {{0.f,0.f,0.f,0.f},{0.f,0.f,0.f,0.f},
                      {0.f,0.f,0.f,0.f},{0.f,0.f,0.f,0.f}};

    for (int kc = 0; kc < Dc; kc += 64) {
        __syncthreads();
#pragma unroll
        for (int p = 0; p < 2; ++p) {
            const int f = tid + p * 256;
            const int row = f >> 3, c8 = (f & 7) << 3;
            *(ushort8*)&Af[row][c8] = *(const ushort8*)(A16 + (size_t)(m0 + row) * Dc + kc + c8);
        }
#pragma unroll
        for (int p = 0; p < 4; ++p) {
            const int f = tid + p * 256;
            const int row = f >> 4, c4 = (f & 15) << 2;
            const float4 t = *(const float4*)(W + (size_t)(n0 + row) * Dc + kc + c4);
            *(ushort4*)&Wf[row][c4] = make_ushort4(f2h(t.x), f2h(t.y), f2h(t.z), f2h(t.w));
        }
        __syncthreads();

        const half8 a0 = *(const half8*)&Af[w * 16 + m][quad * 8];
        const half8 a1 = *(const half8*)&Af[w * 16 + m][32 + quad * 8];
#pragma unroll
        for (int nn = 0; nn < 4; ++nn) {
            const half8 b0 = *(const half8*)&Wf[nn * 16 + m][quad * 8];
            const half8 b1 = *(const half8*)&Wf[nn * 16 + m][32 + quad * 8];
            acc[nn] = __builtin_amdgcn_mfma_f32_16x16x32_f16(a0, b0, acc[nn], 0, 0, 0);
            acc[nn] = __builtin_amdgcn_mfma_f32_16x16x32_f16(a1, b1, acc[nn], 0, 0, 0);
        }
    }

#pragma unroll
    for (int nn = 0; nn < 4; ++nn) {
        const int col = n0 + nn * 16 + m;
#pragma unroll
        for (int r = 0; r < 4; ++r) {
            const int row = m0 + w * 16 + quad * 4 + r;
            __builtin_nontemporal_store(acc[nn][r], C + (size_t)row * Dc + col);
        }
    }
}

extern "C" void kernel_launch(void* const* d_in, const int* in_sizes, int n_in,
                              void* d_out, int out_size, void* d_ws, size_t ws_size,
                              hipStream_t stream) {
    const float* hs   = (const float*)d_in[0];
    const float* cosb = (const float*)d_in[2];
    const float* sinb = (const float*)d_in[3];
    const float* Wq   = (const float*)d_in[4];
    const float* Wk   = (const float*)d_in[5];
    const float* Wv   = (const float*)d_in[6];
    const float* Wo   = (const float*)d_in[7];

    float* attn_output = (float*)d_out;                         // (B,L,D)
    float* attn        = attn_output + (size_t)Mrows * Dc;      // (B,H,L,L)

    const size_t seg = (size_t)Bc * Hc * Lc * HDc;              // 3,145,728 elems
    unsigned short* q16  = (unsigned short*)d_ws;
    unsigned short* k16  = q16 + seg;
    unsigned short* vT16 = k16 + seg;                           // (b,h,hd,l)
    unsigned short* o16  = vT16 + seg;                          // (b,l,Dc)

    const dim3 blk(256);

    // 3 launches: fused QKV+RoPE+V^T, attention (balanced qt bands), out proj
    gemm_qkv<<<dim3(36, Mrows / 64), blk, 0, stream>>>(hs, Wq, Wk, Wv, cosb, sinb,
                                                       q16, k16, vT16);
    attn_kernel<<<dim3(Lc / 64, Bc * Hc), blk, 0, stream>>>(q16, k16, vT16, attn, o16);
    gemm_out<<<dim3(Dc / 64, Mrows / 64), blk, 0, stream>>>(o16, Wo, attn_output);
}

// Round 5
// 573.263 us; speedup vs baseline: 1.2042x; 1.0230x over previous
//
#include <hip/hip_runtime.h>
#include <cstddef>

// Problem constants (B, L, D, H, HD) = (2, 2048, 768, 12, 64)
#define Bc   2
#define Lc   2048
#define Dc   768
#define Hc   12
#define HDc  64
#define Mrows (Bc * Lc)
#define PAD  72   // ushorts; 144 B row stride keeps b128 reads bank-balanced & 16B-aligned

typedef _Float16 half8 __attribute__((ext_vector_type(8)));
typedef unsigned short ushort8 __attribute__((ext_vector_type(8)));
typedef __attribute__((ext_vector_type(4))) float floatx4;

__device__ __forceinline__ float silu_f(float x) {
    return x / (1.0f + __expf(-x));
}
__device__ __forceinline__ unsigned short f2h(float x) {
    _Float16 h = (_Float16)x;                       // v_cvt_f16_f32, RNE
    return __builtin_bit_cast(unsigned short, h);
}

// ---------------------------------------------------------------------------
// Fused QKV projection, 128x128 tile (2x2 waves, acc[4][4]).
// grid (18, 32): x = which*6 + xb (which: 0=Q 1=K 2=V), y = m-block (128 rows).
// Halves LLC/L2 re-read traffic vs 64x64 (A re-read 36->18, W 64->32) and
// quarters cvt-VALU per output. RoPE fused for Q/K (two heads per tile, one
// per wave-column); V stored transposed.
// ---------------------------------------------------------------------------
__global__ __launch_bounds__(256)
void gemm_qkv(const float* __restrict__ hs,
              const float* __restrict__ Wq, const float* __restrict__ Wk,
              const float* __restrict__ Wv,
              const float* __restrict__ cosb, const float* __restrict__ sinb,
              unsigned short* __restrict__ q16, unsigned short* __restrict__ k16,
              unsigned short* __restrict__ vT16) {
    __shared__ unsigned short Af[128][PAD];
    __shared__ unsigned short Wf[128][PAD];
    const int tid  = threadIdx.x;
    const int lane = tid & 63, w = tid >> 6;
    const int m = lane & 15, quad = lane >> 4;
    const int wr = w >> 1, wc = w & 1;              // 2x2 wave grid
    const int m0 = blockIdx.y * 128;
    const int nblk = blockIdx.x;
    const int which = nblk / 6;                     // 0=Q 1=K 2=V (block-uniform)
    const int n0 = (nblk - which * 6) * 128;        // column offset within its matrix
    const float* __restrict__ W = (which == 0) ? Wq : (which == 1) ? Wk : Wv;

    floatx4 acc[4][4] = {};

    for (int kc = 0; kc < Dc; kc += 64) {
        __syncthreads();
#pragma unroll
        for (int p = 0; p < 8; ++p) {
            const int f = tid + p * 256;
            const int row = f >> 4, c4 = (f & 15) << 2;
            const float4 ta = *(const float4*)(hs + (size_t)(m0 + row) * Dc + kc + c4);
            *(ushort4*)&Af[row][c4] = make_ushort4(f2h(ta.x), f2h(ta.y), f2h(ta.z), f2h(ta.w));
            const float4 tw = *(const float4*)(W + (size_t)(n0 + row) * Dc + kc + c4);
            *(ushort4*)&Wf[row][c4] = make_ushort4(f2h(tw.x), f2h(tw.y), f2h(tw.z), f2h(tw.w));
        }
        __syncthreads();

#pragma unroll
        for (int half = 0; half < 2; ++half) {
            half8 av[4], bv[4];
#pragma unroll
            for (int mi = 0; mi < 4; ++mi)
                av[mi] = *(const half8*)&Af[wr * 64 + mi * 16 + m][half * 32 + quad * 8];
#pragma unroll
            for (int ni = 0; ni < 4; ++ni)
                bv[ni] = *(const half8*)&Wf[wc * 64 + ni * 16 + m][half * 32 + quad * 8];
#pragma unroll
            for (int mi = 0; mi < 4; ++mi)
#pragma unroll
                for (int ni = 0; ni < 4; ++ni)
                    acc[mi][ni] = __builtin_amdgcn_mfma_f32_16x16x32_f16(av[mi], bv[ni], acc[mi][ni], 0, 0, 0);
        }
    }

    // D frag: col = n0 + wc*64 + ni*16 + m, row = m0 + wr*64 + mi*16 + quad*4 + r.
    if (which < 2) {
        // Q or K: silu (fp32) -> RoPE (fp32) -> fp16 store to (b,h,l,hd)
        unsigned short* __restrict__ dst = which ? k16 : q16;
        const int h = (n0 >> 6) + wc;               // wave column picks the head
#pragma unroll
        for (int mi = 0; mi < 4; ++mi)
#pragma unroll
        for (int r = 0; r < 4; ++r) {
            const int row = m0 + wr * 64 + mi * 16 + quad * 4 + r;
            const int b = row >> 11, l = row & (Lc - 1);
            const size_t cb   = ((size_t)b * Lc + l) * HDc;
            const size_t base = ((size_t)(b * Hc + h) * Lc + l) * HDc;
            const float ya = silu_f(acc[mi][0][r]);     // hd = m       (x1)
            const float yb = silu_f(acc[mi][1][r]);     // hd = m+16    (x1)
            const float yc = silu_f(acc[mi][2][r]);     // hd = m+32    (x2)
            const float yd = silu_f(acc[mi][3][r]);     // hd = m+48    (x2)
            dst[base + m]      = f2h(ya * cosb[cb + m]      - yc * sinb[cb + m]);
            dst[base + m + 16] = f2h(yb * cosb[cb + m + 16] - yd * sinb[cb + m + 16]);
            dst[base + m + 32] = f2h(yc * cosb[cb + m + 32] + ya * sinb[cb + m + 32]);
            dst[base + m + 48] = f2h(yd * cosb[cb + m + 48] + yb * sinb[cb + m + 48]);
        }
    } else {
        // V: silu, fp16 store TRANSPOSED to (b,h,hd,l)
#pragma unroll
        for (int mi = 0; mi < 4; ++mi)
#pragma unroll
        for (int ni = 0; ni < 4; ++ni) {
            const int col = n0 + wc * 64 + ni * 16 + m;
            const int h = col >> 6, hd = col & 63;
            const int row0 = m0 + wr * 64 + mi * 16 + quad * 4;
            const int b = row0 >> 11, l0 = row0 & (Lc - 1);
            const ushort4 hh = make_ushort4(f2h(silu_f(acc[mi][ni][0])), f2h(silu_f(acc[mi][ni][1])),
                                            f2h(silu_f(acc[mi][ni][2])), f2h(silu_f(acc[mi][ni][3])));
            *(ushort4*)(vT16 + ((size_t)(b * Hc + h) * HDc + hd) * Lc + l0) = hh;
        }
    }
}

// ---------------------------------------------------------------------------
// Fused attention. Register-staged K/V double buffering (T14) + LDS-staged
// S-tile stores: phase 1 writes the fp32 S-tile to Sf (LDS); after the
// existing post-phase-2 barrier, flat threads store it 256B-contiguous per
// row (full 128B lines -> no ECC partial-line RMW on the 402 MB attn write).
// Sf unions over Qf (dead after the bq register load; one-time barrier
// protects the alias). Ps stays wave-private -> still no phase1/2 barrier.
// ---------------------------------------------------------------------------
__global__ __launch_bounds__(256)
void attn_kernel(const unsigned short* __restrict__ q16,
                 const unsigned short* __restrict__ k16,
                 const unsigned short* __restrict__ vT16,
                 float* __restrict__ attn_out,
                 unsigned short* __restrict__ o16) {
    __shared__ unsigned short Kf[64][PAD];   // [kj][hd]
    __shared__ unsigned short Vt[64][PAD];   // [hd][kj]
    __shared__ unsigned short Ps[64][PAD];   // [q][kj]  (wave-private rows)
    __shared__ float Sf[64][68];             // fp32 S-tile; also hosts Qf early
    unsigned short (*Qf)[PAD] = (unsigned short(*)[PAD])&Sf[0][0];  // 9.2KB < 17.4KB

    const int tid  = threadIdx.x;
    const int lane = tid & 63, w = tid >> 6;
    const int m = lane & 15, quad = lane >> 4;

    // balanced qt bands (per-CU work ~constant under round-robin dispatch)
    const int x = blockIdx.x;
    const int bh = blockIdx.y;
    const int band = bh >> 3;
    int qt;
    if (band == 0)      qt = x;
    else if (band == 1) qt = (x + 16) & 31;
    else                qt = (x < 16) ? (30 - 2 * x) : (63 - 2 * x);

    const int b = bh / Hc, h = bh - b * Hc;
    const size_t qkv = (size_t)bh * Lc * HDc;
    const float invL = 1.0f / (float)Lc;

    // staging geometry: 8 threads per row, 16B each -> 1 KB contiguous per wave
    const int srow = tid >> 3, sc8 = (tid & 7) << 3;
    const unsigned short* kbase = k16 + qkv;
    const unsigned short* vbase = vT16 + (size_t)bh * HDc * Lc;

    // Stage Q tile (fp16, 8 KB) into the Sf/Qf union
    {
        const unsigned short* qp = q16 + qkv + (size_t)(qt * 64) * HDc;
        *(ushort8*)&Qf[srow][sc8]      = *(const ushort8*)(qp + srow * HDc + sc8);
        *(ushort8*)&Qf[srow + 32][sc8] = *(const ushort8*)(qp + (srow + 32) * HDc + sc8);
    }

    // Prologue: load + LDS-write tile kt=0
    ushort8 kreg0, kreg1, vreg0, vreg1;
    kreg0 = *(const ushort8*)(kbase + srow * HDc + sc8);
    kreg1 = *(const ushort8*)(kbase + (srow + 32) * HDc + sc8);
    vreg0 = *(const ushort8*)(vbase + (size_t)srow * Lc + sc8);
    vreg1 = *(const ushort8*)(vbase + (size_t)(srow + 32) * Lc + sc8);
    *(ushort8*)&Kf[srow][sc8]      = kreg0;
    *(ushort8*)&Kf[srow + 32][sc8] = kreg1;
    *(ushort8*)&Vt[srow][sc8]      = vreg0;
    *(ushort8*)&Vt[srow + 32][sc8] = vreg1;
    __syncthreads();                                // Qf + tile 0 visible

    // Q as B-operand (fixed per wave): n = q = w*16 + m, k = hd
    const half8 bq0 = *(const half8*)&Qf[w * 16 + m][quad * 8];
    const half8 bq1 = *(const half8*)&Qf[w * 16 + m][32 + quad * 8];
    __syncthreads();   // all bq reads done before Sf (aliases Qf) is written

    floatx4 oacc[4] = {{0.f,0.f,0.f,0.f},{0.f,0.f,0.f,0.f},
                       {0.f,0.f,0.f,0.f},{0.f,0.f,0.f,0.f}};
    float* attn_base = attn_out + (size_t)bh * Lc * Lc;
    const int gi = qt * 64 + w * 16 + m;            // this lane's q row

    for (int kt = 0; kt <= qt; ++kt) {
        // ---- async-stage: issue kt+1 loads now; latency hides under MFMA ----
        if (kt < qt) {
            const unsigned short* kp = kbase + (size_t)((kt + 1) * 64) * HDc;
            const unsigned short* vp = vbase + (kt + 1) * 64;
            kreg0 = *(const ushort8*)(kp + srow * HDc + sc8);
            kreg1 = *(const ushort8*)(kp + (srow + 32) * HDc + sc8);
            vreg0 = *(const ushort8*)(vp + (size_t)srow * Lc + sc8);
            vreg1 = *(const ushort8*)(vp + (size_t)(srow + 32) * Lc + sc8);
        }

        // ---- Phase 1: S^T[kj][q] = sum_hd K[kj][hd] * Q[q][hd] ----
        const bool diag = (kt == qt);
#pragma unroll
        for (int mm = 0; mm < 4; ++mm) {
            const half8 ak0 = *(const half8*)&Kf[mm * 16 + m][quad * 8];
            const half8 ak1 = *(const half8*)&Kf[mm * 16 + m][32 + quad * 8];
            floatx4 s = {0.f, 0.f, 0.f, 0.f};
            s = __builtin_amdgcn_mfma_f32_16x16x32_f16(ak0, bq0, s, 0, 0, 0);
            s = __builtin_amdgcn_mfma_f32_16x16x32_f16(ak1, bq1, s, 0, 0, 0);
            // D: col = q = w*16+m (fixed), row = kj = mm*16 + quad*4 + r
            const int kj0 = mm * 16 + quad * 4;
            const int gj0 = kt * 64 + kj0;
            float v[4];
#pragma unroll
            for (int r = 0; r < 4; ++r) {
                float val = s[r];
                v[r] = (diag && (gj0 + r) > gi) ? 0.0f : silu_f(val) * invL;
            }
            const floatx4 vv = {v[0], v[1], v[2], v[3]};
            *(floatx4*)&Sf[w * 16 + m][kj0] = vv;   // fp32 tile to LDS
            *(ushort4*)&Ps[w * 16 + m][kj0] = make_ushort4(f2h(v[0]), f2h(v[1]), f2h(v[2]), f2h(v[3]));
        }

        // ---- Phase 2 (no barrier: Ps rows are wave-private, DS is in-order) ----
        const half8 ap0 = *(const half8*)&Ps[w * 16 + m][quad * 8];
        const half8 ap1 = *(const half8*)&Ps[w * 16 + m][32 + quad * 8];
#pragma unroll
        for (int nn = 0; nn < 4; ++nn) {
            const half8 bv0 = *(const half8*)&Vt[nn * 16 + m][quad * 8];
            const half8 bv1 = *(const half8*)&Vt[nn * 16 + m][32 + quad * 8];
            oacc[nn] = __builtin_amdgcn_mfma_f32_16x16x32_f16(ap0, bv0, oacc[nn], 0, 0, 0);
            oacc[nn] = __builtin_amdgcn_mfma_f32_16x16x32_f16(ap1, bv1, oacc[nn], 0, 0, 0);
        }

        __syncthreads();   // Kf/Vt reads done, Sf complete, all waves

        // ---- coalesced S-tile store: 4 rows x 256B contiguous per wave-instr ----
#pragma unroll
        for (int p = 0; p < 4; ++p) {
            const int f = tid + p * 256;
            const int row = f >> 4, c = (f & 15) << 2;
            const floatx4 sv = *(const floatx4*)&Sf[row][c];
            __builtin_nontemporal_store(sv,
                (floatx4*)(attn_base + (size_t)(qt * 64 + row) * Lc + kt * 64 + c));
        }

        if (kt < qt) {
            *(ushort8*)&Kf[srow][sc8]      = kreg0; // waits only on the 4 loads
            *(ushort8*)&Kf[srow + 32][sc8] = kreg1;
            *(ushort8*)&Vt[srow][sc8]      = vreg0;
            *(ushort8*)&Vt[srow + 32][sc8] = vreg1;
            __syncthreads();                        // tile kt+1 visible
        }
    }

    // Zero-fill strictly-upper tiles (silu(-1e9)/L == -0.0)
    {
        const int tx = tid & 15, ty = tid >> 4;
        const floatx4 z = {0.f, 0.f, 0.f, 0.f};
#pragma unroll 1
        for (int kt2 = qt + 1; kt2 < Lc / 64; ++kt2) {
#pragma unroll
            for (int i = 0; i < 4; ++i) {
                const int gi2 = qt * 64 + (ty << 2) + i;
                __builtin_nontemporal_store(z,
                    (floatx4*)(attn_base + (size_t)gi2 * Lc + kt2 * 64 + (tx << 2)));
            }
        }
    }

    // out store: D col = hd = nn*16+m, row = q = w*16 + quad*4 + r
#pragma unroll
    for (int nn = 0; nn < 4; ++nn)
#pragma unroll
        for (int r = 0; r < 4; ++r) {
            const int gi2 = qt * 64 + w * 16 + quad * 4 + r;
            o16[((size_t)b * Lc + gi2) * Dc + h * HDc + nn * 16 + m] = f2h(oacc[nn][r]);
        }
}

// ---------------------------------------------------------------------------
// Output projection: attn_output[m][n] = sum_k o16[m][k] * Wo[n][k], fp32 out.
// ---------------------------------------------------------------------------
__global__ __launch_bounds__(256)
void gemm_out(const unsigned short* __restrict__ A16, const float* __restrict__ W,
              float* __restrict__ C) {
    __shared__ unsigned short Af[64][PAD];
    __shared__ unsigned short Wf[64][PAD];
    const int tid  = threadIdx.x;
    const int lane = tid & 63, w = tid >> 6;
    const int m = lane & 15, quad = lane >> 4;
    const int m0 = blockIdx.y * 64, n0 = blockIdx.x * 64;

    floatx4 acc[4] = {{0.f,0.f,0.f,0.f},{0.f,0.f,0.f,0.f},
                      {0.f,0.f,0.f,0.f},{0.f,0.f,0.f,0.f}};

    for (int kc = 0; kc < Dc; kc += 64) {
        __syncthreads();
#pragma unroll
        for (int p = 0; p < 2; ++p) {
            const int f = tid + p * 256;
            const int row = f >> 3, c8 = (f & 7) << 3;
            *(ushort8*)&Af[row][c8] = *(const ushort8*)(A16 + (size_t)(m0 + row) * Dc + kc + c8);
        }
#pragma unroll
        for (int p = 0; p < 4; ++p) {
            const int f = tid + p * 256;
            const int row = f >> 4, c4 = (f & 15) << 2;
            const float4 t = *(const float4*)(W + (size_t)(n0 + row) * Dc + kc + c4);
            *(ushort4*)&Wf[row][c4] = make_ushort4(f2h(t.x), f2h(t.y), f2h(t.z), f2h(t.w));
        }
        __syncthreads();

        const half8 a0 = *(const half8*)&Af[w * 16 + m][quad * 8];
        const half8 a1 = *(const half8*)&Af[w * 16 + m][32 + quad * 8];
#pragma unroll
        for (int nn = 0; nn < 4; ++nn) {
            const half8 b0 = *(const half8*)&Wf[nn * 16 + m][quad * 8];
            const half8 b1 = *(const half8*)&Wf[nn * 16 + m][32 + quad * 8];
            acc[nn] = __builtin_amdgcn_mfma_f32_16x16x32_f16(a0, b0, acc[nn], 0, 0, 0);
            acc[nn] = __builtin_amdgcn_mfma_f32_16x16x32_f16(a1, b1, acc[nn], 0, 0, 0);
        }
    }

#pragma unroll
    for (int nn = 0; nn < 4; ++nn) {
        const int col = n0 + nn * 16 + m;
#pragma unroll
        for (int r = 0; r < 4; ++r) {
            const int row = m0 + w * 16 + quad * 4 + r;
            __builtin_nontemporal_store(acc[nn][r], C + (size_t)row * Dc + col);
        }
    }
}

extern "C" void kernel_launch(void* const* d_in, const int* in_sizes, int n_in,
                              void* d_out, int out_size, void* d_ws, size_t ws_size,
                              hipStream_t stream) {
    const float* hs   = (const float*)d_in[0];
    const float* cosb = (const float*)d_in[2];
    const float* sinb = (const float*)d_in[3];
    const float* Wq   = (const float*)d_in[4];
    const float* Wk   = (const float*)d_in[5];
    const float* Wv   = (const float*)d_in[6];
    const float* Wo   = (const float*)d_in[7];

    float* attn_output = (float*)d_out;                         // (B,L,D)
    float* attn        = attn_output + (size_t)Mrows * Dc;      // (B,H,L,L)

    const size_t seg = (size_t)Bc * Hc * Lc * HDc;              // 3,145,728 elems
    unsigned short* q16  = (unsigned short*)d_ws;
    unsigned short* k16  = q16 + seg;
    unsigned short* vT16 = k16 + seg;                           // (b,h,hd,l)
    unsigned short* o16  = vT16 + seg;                          // (b,l,Dc)

    const dim3 blk(256);

    // 3 launches: fused QKV+RoPE+V^T (128x128 tiles), attention, out proj
    gemm_qkv<<<dim3(18, Mrows / 128), blk, 0, stream>>>(hs, Wq, Wk, Wv, cosb, sinb,
                                                        q16, k16, vT16);
    attn_kernel<<<dim3(Lc / 64, Bc * Hc), blk, 0, stream>>>(q16, k16, vT16, attn, o16);
    gemm_out<<<dim3(Dc / 64, Mrows / 64), blk, 0, stream>>>(o16, Wo, attn_output);
}

// Round 6
// 573.222 us; speedup vs baseline: 1.2043x; 1.0001x over previous
//
#include <hip/hip_runtime.h>
#include <cstddef>

// Problem constants (B, L, D, H, HD) = (2, 2048, 768, 12, 64)
#define Bc   2
#define Lc   2048
#define Dc   768
#define Hc   12
#define HDc  64
#define Mrows (Bc * Lc)
#define PAD  72   // ushorts; 144 B row stride keeps b128 reads bank-balanced & 16B-aligned

typedef _Float16 half8 __attribute__((ext_vector_type(8)));
typedef unsigned short ushort8 __attribute__((ext_vector_type(8)));
typedef __attribute__((ext_vector_type(4))) float floatx4;

__device__ __forceinline__ float silu_f(float x) {
    return x / (1.0f + __expf(-x));
}
__device__ __forceinline__ unsigned short f2h(float x) {
    _Float16 h = (_Float16)x;                       // v_cvt_f16_f32, RNE
    return __builtin_bit_cast(unsigned short, h);
}

// ---------------------------------------------------------------------------
// Fused QKV projection, 128x128 tile (2x2 waves, acc[4][4]).
// grid (18, 32): x = which*6 + xb (which: 0=Q 1=K 2=V), y = m-block (128 rows).
// RoPE fused for Q/K (two heads per tile, one per wave-column); V stored ^T.
// ---------------------------------------------------------------------------
__global__ __launch_bounds__(256)
void gemm_qkv(const float* __restrict__ hs,
              const float* __restrict__ Wq, const float* __restrict__ Wk,
              const float* __restrict__ Wv,
              const float* __restrict__ cosb, const float* __restrict__ sinb,
              unsigned short* __restrict__ q16, unsigned short* __restrict__ k16,
              unsigned short* __restrict__ vT16) {
    __shared__ unsigned short Af[128][PAD];
    __shared__ unsigned short Wf[128][PAD];
    const int tid  = threadIdx.x;
    const int lane = tid & 63, w = tid >> 6;
    const int m = lane & 15, quad = lane >> 4;
    const int wr = w >> 1, wc = w & 1;              // 2x2 wave grid
    const int m0 = blockIdx.y * 128;
    const int nblk = blockIdx.x;
    const int which = nblk / 6;                     // 0=Q 1=K 2=V (block-uniform)
    const int n0 = (nblk - which * 6) * 128;        // column offset within its matrix
    const float* __restrict__ W = (which == 0) ? Wq : (which == 1) ? Wk : Wv;

    floatx4 acc[4][4] = {};

    for (int kc = 0; kc < Dc; kc += 64) {
        __syncthreads();
#pragma unroll
        for (int p = 0; p < 8; ++p) {
            const int f = tid + p * 256;
            const int row = f >> 4, c4 = (f & 15) << 2;
            const float4 ta = *(const float4*)(hs + (size_t)(m0 + row) * Dc + kc + c4);
            *(ushort4*)&Af[row][c4] = make_ushort4(f2h(ta.x), f2h(ta.y), f2h(ta.z), f2h(ta.w));
            const float4 tw = *(const float4*)(W + (size_t)(n0 + row) * Dc + kc + c4);
            *(ushort4*)&Wf[row][c4] = make_ushort4(f2h(tw.x), f2h(tw.y), f2h(tw.z), f2h(tw.w));
        }
        __syncthreads();

#pragma unroll
        for (int half = 0; half < 2; ++half) {
            half8 av[4], bv[4];
#pragma unroll
            for (int mi = 0; mi < 4; ++mi)
                av[mi] = *(const half8*)&Af[wr * 64 + mi * 16 + m][half * 32 + quad * 8];
#pragma unroll
            for (int ni = 0; ni < 4; ++ni)
                bv[ni] = *(const half8*)&Wf[wc * 64 + ni * 16 + m][half * 32 + quad * 8];
#pragma unroll
            for (int mi = 0; mi < 4; ++mi)
#pragma unroll
                for (int ni = 0; ni < 4; ++ni)
                    acc[mi][ni] = __builtin_amdgcn_mfma_f32_16x16x32_f16(av[mi], bv[ni], acc[mi][ni], 0, 0, 0);
        }
    }

    // D frag: col = n0 + wc*64 + ni*16 + m, row = m0 + wr*64 + mi*16 + quad*4 + r.
    if (which < 2) {
        // Q or K: silu (fp32) -> RoPE (fp32) -> fp16 store to (b,h,l,hd)
        unsigned short* __restrict__ dst = which ? k16 : q16;
        const int h = (n0 >> 6) + wc;               // wave column picks the head
#pragma unroll
        for (int mi = 0; mi < 4; ++mi)
#pragma unroll
        for (int r = 0; r < 4; ++r) {
            const int row = m0 + wr * 64 + mi * 16 + quad * 4 + r;
            const int b = row >> 11, l = row & (Lc - 1);
            const size_t cb   = ((size_t)b * Lc + l) * HDc;
            const size_t base = ((size_t)(b * Hc + h) * Lc + l) * HDc;
            const float ya = silu_f(acc[mi][0][r]);     // hd = m       (x1)
            const float yb = silu_f(acc[mi][1][r]);     // hd = m+16    (x1)
            const float yc = silu_f(acc[mi][2][r]);     // hd = m+32    (x2)
            const float yd = silu_f(acc[mi][3][r]);     // hd = m+48    (x2)
            dst[base + m]      = f2h(ya * cosb[cb + m]      - yc * sinb[cb + m]);
            dst[base + m + 16] = f2h(yb * cosb[cb + m + 16] - yd * sinb[cb + m + 16]);
            dst[base + m + 32] = f2h(yc * cosb[cb + m + 32] + ya * sinb[cb + m + 32]);
            dst[base + m + 48] = f2h(yd * cosb[cb + m + 48] + yb * sinb[cb + m + 48]);
        }
    } else {
        // V: silu, fp16 store TRANSPOSED to (b,h,hd,l)
#pragma unroll
        for (int mi = 0; mi < 4; ++mi)
#pragma unroll
        for (int ni = 0; ni < 4; ++ni) {
            const int col = n0 + wc * 64 + ni * 16 + m;
            const int h = col >> 6, hd = col & 63;
            const int row0 = m0 + wr * 64 + mi * 16 + quad * 4;
            const int b = row0 >> 11, l0 = row0 & (Lc - 1);
            const ushort4 hh = make_ushort4(f2h(silu_f(acc[mi][ni][0])), f2h(silu_f(acc[mi][ni][1])),
                                            f2h(silu_f(acc[mi][ni][2])), f2h(silu_f(acc[mi][ni][3])));
            *(ushort4*)(vT16 + ((size_t)(b * Hc + h) * HDc + hd) * Lc + l0) = hh;
        }
    }
}

// ---------------------------------------------------------------------------
// Fused attention. Register-staged K/V double buffering (T14) + LDS-staged
// S-tile stores (full 128B lines). REGULAR stores (A/B vs R4's nontemporal):
// write-back L2/LLC gives the memory controller a 32MB+256MB reorder window
// to drain our 256B-chunk / 8KB-stride scatter with DRAM page locality; the
// harness fill kernel proves regular streaming stores hit 6.3 TB/s.
// ---------------------------------------------------------------------------
__global__ __launch_bounds__(256)
void attn_kernel(const unsigned short* __restrict__ q16,
                 const unsigned short* __restrict__ k16,
                 const unsigned short* __restrict__ vT16,
                 float* __restrict__ attn_out,
                 unsigned short* __restrict__ o16) {
    __shared__ unsigned short Kf[64][PAD];   // [kj][hd]
    __shared__ unsigned short Vt[64][PAD];   // [hd][kj]
    __shared__ unsigned short Ps[64][PAD];   // [q][kj]  (wave-private rows)
    __shared__ float Sf[64][68];             // fp32 S-tile; also hosts Qf early
    unsigned short (*Qf)[PAD] = (unsigned short(*)[PAD])&Sf[0][0];  // 9.2KB < 17.4KB

    const int tid  = threadIdx.x;
    const int lane = tid & 63, w = tid >> 6;
    const int m = lane & 15, quad = lane >> 4;

    // balanced qt bands (per-CU work ~constant under round-robin dispatch)
    const int x = blockIdx.x;
    const int bh = blockIdx.y;
    const int band = bh >> 3;
    int qt;
    if (band == 0)      qt = x;
    else if (band == 1) qt = (x + 16) & 31;
    else                qt = (x < 16) ? (30 - 2 * x) : (63 - 2 * x);

    const int b = bh / Hc, h = bh - b * Hc;
    const size_t qkv = (size_t)bh * Lc * HDc;
    const float invL = 1.0f / (float)Lc;

    // staging geometry: 8 threads per row, 16B each -> 1 KB contiguous per wave
    const int srow = tid >> 3, sc8 = (tid & 7) << 3;
    const unsigned short* kbase = k16 + qkv;
    const unsigned short* vbase = vT16 + (size_t)bh * HDc * Lc;

    // Stage Q tile (fp16, 8 KB) into the Sf/Qf union
    {
        const unsigned short* qp = q16 + qkv + (size_t)(qt * 64) * HDc;
        *(ushort8*)&Qf[srow][sc8]      = *(const ushort8*)(qp + srow * HDc + sc8);
        *(ushort8*)&Qf[srow + 32][sc8] = *(const ushort8*)(qp + (srow + 32) * HDc + sc8);
    }

    // Prologue: load + LDS-write tile kt=0
    ushort8 kreg0, kreg1, vreg0, vreg1;
    kreg0 = *(const ushort8*)(kbase + srow * HDc + sc8);
    kreg1 = *(const ushort8*)(kbase + (srow + 32) * HDc + sc8);
    vreg0 = *(const ushort8*)(vbase + (size_t)srow * Lc + sc8);
    vreg1 = *(const ushort8*)(vbase + (size_t)(srow + 32) * Lc + sc8);
    *(ushort8*)&Kf[srow][sc8]      = kreg0;
    *(ushort8*)&Kf[srow + 32][sc8] = kreg1;
    *(ushort8*)&Vt[srow][sc8]      = vreg0;
    *(ushort8*)&Vt[srow + 32][sc8] = vreg1;
    __syncthreads();                                // Qf + tile 0 visible

    // Q as B-operand (fixed per wave): n = q = w*16 + m, k = hd
    const half8 bq0 = *(const half8*)&Qf[w * 16 + m][quad * 8];
    const half8 bq1 = *(const half8*)&Qf[w * 16 + m][32 + quad * 8];
    __syncthreads();   // all bq reads done before Sf (aliases Qf) is written

    floatx4 oacc[4] = {{0.f,0.f,0.f,0.f},{0.f,0.f,0.f,0.f},
                       {0.f,0.f,0.f,0.f},{0.f,0.f,0.f,0.f}};
    float* attn_base = attn_out + (size_t)bh * Lc * Lc;
    const int gi = qt * 64 + w * 16 + m;            // this lane's q row

    for (int kt = 0; kt <= qt; ++kt) {
        // ---- async-stage: issue kt+1 loads now; latency hides under MFMA ----
        if (kt < qt) {
            const unsigned short* kp = kbase + (size_t)((kt + 1) * 64) * HDc;
            const unsigned short* vp = vbase + (kt + 1) * 64;
            kreg0 = *(const ushort8*)(kp + srow * HDc + sc8);
            kreg1 = *(const ushort8*)(kp + (srow + 32) * HDc + sc8);
            vreg0 = *(const ushort8*)(vp + (size_t)srow * Lc + sc8);
            vreg1 = *(const ushort8*)(vp + (size_t)(srow + 32) * Lc + sc8);
        }

        // ---- Phase 1: S^T[kj][q] = sum_hd K[kj][hd] * Q[q][hd] ----
        const bool diag = (kt == qt);
#pragma unroll
        for (int mm = 0; mm < 4; ++mm) {
            const half8 ak0 = *(const half8*)&Kf[mm * 16 + m][quad * 8];
            const half8 ak1 = *(const half8*)&Kf[mm * 16 + m][32 + quad * 8];
            floatx4 s = {0.f, 0.f, 0.f, 0.f};
            s = __builtin_amdgcn_mfma_f32_16x16x32_f16(ak0, bq0, s, 0, 0, 0);
            s = __builtin_amdgcn_mfma_f32_16x16x32_f16(ak1, bq1, s, 0, 0, 0);
            // D: col = q = w*16+m (fixed), row = kj = mm*16 + quad*4 + r
            const int kj0 = mm * 16 + quad * 4;
            const int gj0 = kt * 64 + kj0;
            float v[4];
#pragma unroll
            for (int r = 0; r < 4; ++r) {
                float val = s[r];
                v[r] = (diag && (gj0 + r) > gi) ? 0.0f : silu_f(val) * invL;
            }
            const floatx4 vv = {v[0], v[1], v[2], v[3]};
            *(floatx4*)&Sf[w * 16 + m][kj0] = vv;   // fp32 tile to LDS
            *(ushort4*)&Ps[w * 16 + m][kj0] = make_ushort4(f2h(v[0]), f2h(v[1]), f2h(v[2]), f2h(v[3]));
        }

        // ---- Phase 2 (no barrier: Ps rows are wave-private, DS is in-order) ----
        const half8 ap0 = *(const half8*)&Ps[w * 16 + m][quad * 8];
        const half8 ap1 = *(const half8*)&Ps[w * 16 + m][32 + quad * 8];
#pragma unroll
        for (int nn = 0; nn < 4; ++nn) {
            const half8 bv0 = *(const half8*)&Vt[nn * 16 + m][quad * 8];
            const half8 bv1 = *(const half8*)&Vt[nn * 16 + m][32 + quad * 8];
            oacc[nn] = __builtin_amdgcn_mfma_f32_16x16x32_f16(ap0, bv0, oacc[nn], 0, 0, 0);
            oacc[nn] = __builtin_amdgcn_mfma_f32_16x16x32_f16(ap1, bv1, oacc[nn], 0, 0, 0);
        }

        __syncthreads();   // Kf/Vt reads done, Sf complete, all waves

        // ---- coalesced S-tile store: 4 rows x 256B contiguous per wave-instr ----
#pragma unroll
        for (int p = 0; p < 4; ++p) {
            const int f = tid + p * 256;
            const int row = f >> 4, c = (f & 15) << 2;
            const floatx4 sv = *(const floatx4*)&Sf[row][c];
            *(floatx4*)(attn_base + (size_t)(qt * 64 + row) * Lc + kt * 64 + c) = sv;
        }

        if (kt < qt) {
            *(ushort8*)&Kf[srow][sc8]      = kreg0; // waits only on the 4 loads
            *(ushort8*)&Kf[srow + 32][sc8] = kreg1;
            *(ushort8*)&Vt[srow][sc8]      = vreg0;
            *(ushort8*)&Vt[srow + 32][sc8] = vreg1;
            __syncthreads();                        // tile kt+1 visible
        }
    }

    // Zero-fill strictly-upper tiles (silu(-1e9)/L == -0.0)
    {
        const int tx = tid & 15, ty = tid >> 4;
        const floatx4 z = {0.f, 0.f, 0.f, 0.f};
#pragma unroll 1
        for (int kt2 = qt + 1; kt2 < Lc / 64; ++kt2) {
#pragma unroll
            for (int i = 0; i < 4; ++i) {
                const int gi2 = qt * 64 + (ty << 2) + i;
                *(floatx4*)(attn_base + (size_t)gi2 * Lc + kt2 * 64 + (tx << 2)) = z;
            }
        }
    }

    // out store: D col = hd = nn*16+m, row = q = w*16 + quad*4 + r
#pragma unroll
    for (int nn = 0; nn < 4; ++nn)
#pragma unroll
        for (int r = 0; r < 4; ++r) {
            const int gi2 = qt * 64 + w * 16 + quad * 4 + r;
            o16[((size_t)b * Lc + gi2) * Dc + h * HDc + nn * 16 + m] = f2h(oacc[nn][r]);
        }
}

// ---------------------------------------------------------------------------
// Output projection: attn_output[m][n] = sum_k o16[m][k] * Wo[n][k], fp32 out.
// ---------------------------------------------------------------------------
__global__ __launch_bounds__(256)
void gemm_out(const unsigned short* __restrict__ A16, const float* __restrict__ W,
              float* __restrict__ C) {
    __shared__ unsigned short Af[64][PAD];
    __shared__ unsigned short Wf[64][PAD];
    const int tid  = threadIdx.x;
    const int lane = tid & 63, w = tid >> 6;
    const int m = lane & 15, quad = lane >> 4;
    const int m0 = blockIdx.y * 64, n0 = blockIdx.x * 64;

    floatx4 acc[4] = {{0.f,0.f,0.f,0.f},{0.f,0.f,0.f,0.f},
                      {0.f,0.f,0.f,0.f},{0.f,0.f,0.f,0.f}};

    for (int kc = 0; kc < Dc; kc += 64) {
        __syncthreads();
#pragma unroll
        for (int p = 0; p < 2; ++p) {
            const int f = tid + p * 256;
            const int row = f >> 3, c8 = (f & 7) << 3;
            *(ushort8*)&Af[row][c8] = *(const ushort8*)(A16 + (size_t)(m0 + row) * Dc + kc + c8);
        }
#pragma unroll
        for (int p = 0; p < 4; ++p) {
            const int f = tid + p * 256;
            const int row = f >> 4, c4 = (f & 15) << 2;
            const float4 t = *(const float4*)(W + (size_t)(n0 + row) * Dc + kc + c4);
            *(ushort4*)&Wf[row][c4] = make_ushort4(f2h(t.x), f2h(t.y), f2h(t.z), f2h(t.w));
        }
        __syncthreads();

        const half8 a0 = *(const half8*)&Af[w * 16 + m][quad * 8];
        const half8 a1 = *(const half8*)&Af[w * 16 + m][32 + quad * 8];
#pragma unroll
        for (int nn = 0; nn < 4; ++nn) {
            const half8 b0 = *(const half8*)&Wf[nn * 16 + m][quad * 8];
            const half8 b1 = *(const half8*)&Wf[nn * 16 + m][32 + quad * 8];
            acc[nn] = __builtin_amdgcn_mfma_f32_16x16x32_f16(a0, b0, acc[nn], 0, 0, 0);
            acc[nn] = __builtin_amdgcn_mfma_f32_16x16x32_f16(a1, b1, acc[nn], 0, 0, 0);
        }
    }

#pragma unroll
    for (int nn = 0; nn < 4; ++nn) {
        const int col = n0 + nn * 16 + m;
#pragma unroll
        for (int r = 0; r < 4; ++r) {
            const int row = m0 + w * 16 + quad * 4 + r;
            C[(size_t)row * Dc + col] = acc[nn][r];
        }
    }
}

extern "C" void kernel_launch(void* const* d_in, const int* in_sizes, int n_in,
                              void* d_out, int out_size, void* d_ws, size_t ws_size,
                              hipStream_t stream) {
    const float* hs   = (const float*)d_in[0];
    const float* cosb = (const float*)d_in[2];
    const float* sinb = (const float*)d_in[3];
    const float* Wq   = (const float*)d_in[4];
    const float* Wk   = (const float*)d_in[5];
    const float* Wv   = (const float*)d_in[6];
    const float* Wo   = (const float*)d_in[7];

    float* attn_output = (float*)d_out;                         // (B,L,D)
    float* attn        = attn_output + (size_t)Mrows * Dc;      // (B,H,L,L)

    const size_t seg = (size_t)Bc * Hc * Lc * HDc;              // 3,145,728 elems
    unsigned short* q16  = (unsigned short*)d_ws;
    unsigned short* k16  = q16 + seg;
    unsigned short* vT16 = k16 + seg;                           // (b,h,hd,l)
    unsigned short* o16  = vT16 + seg;                          // (b,l,Dc)

    const dim3 blk(256);

    // 3 launches: fused QKV+RoPE+V^T (128x128 tiles), attention, out proj
    gemm_qkv<<<dim3(18, Mrows / 128), blk, 0, stream>>>(hs, Wq, Wk, Wv, cosb, sinb,
                                                        q16, k16, vT16);
    attn_kernel<<<dim3(Lc / 64, Bc * Hc), blk, 0, stream>>>(q16, k16, vT16, attn, o16);
    gemm_out<<<dim3(Dc / 64, Mrows / 64), blk, 0, stream>>>(o16, Wo, attn_output);
}